// Round 5
// baseline (126.151 us; speedup 1.0000x reference)
//
#include <hip/hip_runtime.h>
#include <hip/hip_bf16.h>
#include <math.h>

// GAT: out = softmax(mask(lrelu(w1 + w2^T), adj)) @ (x@W) + bias
// R5 = R4 with bits row-stride fixed (128 u64/row, 8MB).
//  k12 : blocks 0..511 = k1 (Wh=x@W, w1/w2 logits, WhT in 32-col tiles)
//        blocks 512+   = k2a: adj(268MB int32) -> bitmask(8MB) via ballot
//  k2b : bitmask + tiled WhT -> masked-exp2 P (LDS-staged) -> MFMA P@Wh + Z
//  k3  : combine column splits, divide by Z, add bias

#define NN    8192
#define INF   256
#define OUTF  64
#define TILE1 16
#define K1B   (NN / TILE1)   // 512 k1 blocks
#define ROWSB 4              // adj rows per k2a block
#define K2AB  (NN / ROWSB)   // 2048 k2a blocks
#define BM    64
#define SPL   8
#define CPS   (NN / SPL)     // 1024
#define KT    256            // cols per super-step
#define NSS   (CPS / KT)     // 4
#define BPR   128            // bits u64 words per row (8192/64)
#define C0    1.0000900040501013f   // expf(9e-5)
#define LOG2E 1.4426950408889634f

typedef __bf16 bf16x8 __attribute__((ext_vector_type(8)));
typedef __bf16 bf16x4 __attribute__((ext_vector_type(4)));
typedef float  f32x4  __attribute__((ext_vector_type(4)));
typedef int    i32x4  __attribute__((ext_vector_type(4)));
typedef unsigned long long u64;

#if __has_builtin(__builtin_amdgcn_exp2f)
#define EXP2(x) __builtin_amdgcn_exp2f(x)
#else
#define EXP2(x) exp2f(x)
#endif

__device__ __forceinline__ __bf16 pcalc(unsigned m, float sv) {
    float el = fmaxf(sv, 0.2f * sv);     // leaky_relu (log2-domain logits)
    float pe = EXP2(el);
    return (__bf16)(m ? pe : C0);
}

// k12: fused projection (k1) + adj->bits compaction (k2a)
__global__ __launch_bounds__(256) void k12(
    const float* __restrict__ x, const float* __restrict__ W,
    const float* __restrict__ alpha, const int* __restrict__ adj,
    __bf16* __restrict__ WhTt, float* __restrict__ w1, float* __restrict__ w2,
    u64* __restrict__ bits)
{
    __shared__ float xs[TILE1 * INF];    // 16 KB (k1 path only)
    __shared__ float shwh[TILE1 * 65];
    const int tid = threadIdx.x;
    const int wave = tid >> 6, lane = tid & 63;

    if (blockIdx.x >= K1B) {
        // ---- k2a: linear adj stream -> bitmask ----
        // chunk c: lane loads cols c*256 + 4*lane .. +3;
        // word e of chunk: bit l = adj[row][c*256 + 4l + e] (stride-4 classes)
        const int row = (blockIdx.x - K1B) * ROWSB + wave;
        const i32x4* ap = (const i32x4*)(adj + (size_t)row * NN);
        u64* brow = bits + (size_t)row * BPR;
#pragma unroll 4
        for (int c = 0; c < 32; ++c) {              // 32 chunks of 256 cols
            i32x4 a = __builtin_nontemporal_load(ap + c * 64 + lane);
            u64 b0 = __ballot(a[0] > 0);
            u64 b1 = __ballot(a[1] > 0);
            u64 b2 = __ballot(a[2] > 0);
            u64 b3 = __ballot(a[3] > 0);
            if (lane == 0) {
                ulonglong4 q; q.x = b0; q.y = b1; q.z = b2; q.w = b3;
                *(ulonglong4*)(brow + c * 4) = q;
            }
        }
        return;
    }

    // ---- k1: Wh = x@W; w1/w2=(Wh@a)*log2e; WhTt = bf16(Wh)^T tiled ----
    const int i0 = blockIdx.x * TILE1;
    const float4* xsrc = (const float4*)(x + (size_t)i0 * INF);
    float4* xdst = (float4*)xs;
#pragma unroll
    for (int it = 0; it < (TILE1 * INF / 4) / 256; ++it)
        xdst[tid + it * 256] = xsrc[tid + it * 256];
    __syncthreads();

    const float a1 = alpha[lane], a2 = alpha[OUTF + lane];
    const int ilbase = wave * 4;

    float acc[4] = {};
#pragma unroll 4
    for (int k4 = 0; k4 < INF / 4; ++k4) {
        float wk0 = W[(4 * k4 + 0) * OUTF + lane];
        float wk1 = W[(4 * k4 + 1) * OUTF + lane];
        float wk2 = W[(4 * k4 + 2) * OUTF + lane];
        float wk3 = W[(4 * k4 + 3) * OUTF + lane];
#pragma unroll
        for (int rr = 0; rr < 4; ++rr) {
            float4 xv = *(const float4*)&xs[(ilbase + rr) * INF + 4 * k4];
            acc[rr] = fmaf(xv.x, wk0, acc[rr]);
            acc[rr] = fmaf(xv.y, wk1, acc[rr]);
            acc[rr] = fmaf(xv.z, wk2, acc[rr]);
            acc[rr] = fmaf(xv.w, wk3, acc[rr]);
        }
    }

#pragma unroll
    for (int rr = 0; rr < 4; ++rr) {
        const int il = ilbase + rr;
        const int i  = i0 + il;
        float a = acc[rr];
        float v1 = a * a1, v2 = a * a2;
#pragma unroll
        for (int off = 32; off > 0; off >>= 1) {
            v1 += __shfl_xor(v1, off);
            v2 += __shfl_xor(v2, off);
        }
        if (lane == 0) { w1[i] = v1 * LOG2E; w2[i] = v2 * LOG2E; }
        shwh[il * 65 + lane] = a;
    }
    __syncthreads();

    // tiled store: WhTt[(j/32)*64*32 + f*32 + j%32]
#pragma unroll
    for (int it = 0; it < (OUTF * TILE1) / 256; ++it) {
        int idx = it * 256 + tid;
        int f = idx / TILE1, il = idx % TILE1;
        int j = i0 + il;
        WhTt[((size_t)(j >> 5) * 64 + f) * 32 + (j & 31)] = (__bf16)shwh[il * 65 + f];
    }
}

// k2b: bits + tiled WhT -> P (LDS) -> 4 MFMA + Z-MFMA
__global__ __launch_bounds__(256) void k2b(
    const u64* __restrict__ bits, const float* __restrict__ w1g,
    const float* __restrict__ w2g, const __bf16* __restrict__ WhTt,
    float* __restrict__ pacc, float* __restrict__ pz)
{
    __shared__ __align__(16) char plds[4 * 16 * KT * 2];  // 32KB: 8KB/wave
    __shared__ float w2s[CPS];                            // 4KB
    __shared__ float w1s[BM];
    const int tid = threadIdx.x;
    const int s  = blockIdx.x & (SPL - 1);   // bid%8 -> XCD-aligned slice
    const int row_tile = blockIdx.x >> 3;
    const int jb = s * CPS;

    ((float4*)w2s)[tid] = ((const float4*)(w2g + jb))[tid];
    if (tid < BM) w1s[tid] = w1g[row_tile * BM + tid];
    __syncthreads();

    const int wave = tid >> 6, lane = tid & 63;
    const int fl = lane & 15, g = lane >> 4;
    const int rw0 = row_tile * BM + wave * 16;

    f32x4 acc0 = {}, acc1 = {}, acc2 = {}, acc3 = {}, accZ = {};
    bf16x8 ones;
#pragma unroll
    for (int e = 0; e < 8; ++e) ones[e] = (__bf16)1.0f;

    char* pb = plds + wave * (16 * KT * 2);

    for (int ss = 0; ss < NSS; ++ss) {
        const int coff = ss * KT;
        const float4 wv = *(const float4*)(w2s + coff + 4 * lane);
        // chunk index within row: global chunk = s*4 + ss (256 cols each)
        const u64* bchunk = bits + (size_t)rw0 * BPR + (s * 4 + ss) * 4;

        // 16 rows: bit-test -> masked exp2 -> swizzled LDS write
#pragma unroll
        for (int r = 0; r < 16; ++r) {
            const float w1r = w1s[wave * 16 + r];
            const u64* bp = bchunk + (size_t)r * BPR;
            u64 b0 = bp[0], b1 = bp[1], b2 = bp[2], b3 = bp[3];
            bf16x4 pv;
            pv[0] = pcalc((unsigned)(b0 >> lane) & 1u, w1r + wv.x);
            pv[1] = pcalc((unsigned)(b1 >> lane) & 1u, w1r + wv.y);
            pv[2] = pcalc((unsigned)(b2 >> lane) & 1u, w1r + wv.z);
            pv[3] = pcalc((unsigned)(b3 >> lane) & 1u, w1r + wv.w);
            *(bf16x4*)(pb + r * (KT * 2) + ((lane * 8) ^ ((r & 7) << 4))) = pv;
        }

        // MFMA: A-frag from own LDS strip, B-frag = 1KB contiguous tiled WhT
#pragma unroll
        for (int t = 0; t < KT / 32; ++t) {
            bf16x8 af = *(const bf16x8*)(
                pb + fl * (KT * 2) + (((t << 6) + (g << 4)) ^ ((fl & 7) << 4)));
            const __bf16* bt = WhTt + ((size_t)(jb + coff + 32 * t) >> 5) * (64 * 32)
                             + fl * 32 + g * 8;
            acc0 = __builtin_amdgcn_mfma_f32_16x16x32_bf16(af, *(const bf16x8*)(bt +    0), acc0, 0, 0, 0);
            acc1 = __builtin_amdgcn_mfma_f32_16x16x32_bf16(af, *(const bf16x8*)(bt +  512), acc1, 0, 0, 0);
            acc2 = __builtin_amdgcn_mfma_f32_16x16x32_bf16(af, *(const bf16x8*)(bt + 1024), acc2, 0, 0, 0);
            acc3 = __builtin_amdgcn_mfma_f32_16x16x32_bf16(af, *(const bf16x8*)(bt + 1536), acc3, 0, 0, 0);
            accZ = __builtin_amdgcn_mfma_f32_16x16x32_bf16(af, ones, accZ, 0, 0, 0);
        }
    }

    // Z row sums (D row = g*4 + i, all cols equal)
    if (fl == 0) {
#pragma unroll
        for (int i = 0; i < 4; ++i)
            pz[(size_t)s * NN + rw0 + 4 * g + i] = accZ[i];
    }
    // numerator: row = rw0 + g*4 + i, col = n*16 + fl
    float* prow = pacc + ((size_t)s * NN + rw0 + 4 * g) * OUTF + fl;
#pragma unroll
    for (int i = 0; i < 4; ++i) {
        __builtin_nontemporal_store(acc0[i], prow + (size_t)i * OUTF + 0);
        __builtin_nontemporal_store(acc1[i], prow + (size_t)i * OUTF + 16);
        __builtin_nontemporal_store(acc2[i], prow + (size_t)i * OUTF + 32);
        __builtin_nontemporal_store(acc3[i], prow + (size_t)i * OUTF + 48);
    }
}

// k3: combine splits, divide by Z, add bias
__global__ __launch_bounds__(256) void k3_final(
    const float* __restrict__ pacc, const float* __restrict__ pz,
    const float* __restrict__ bias, float* __restrict__ out)
{
    const int t = blockIdx.x * 256 + threadIdx.x;
    const int i = t >> 6, f = t & 63;
    float num = 0.f, z = 0.f;
#pragma unroll
    for (int s = 0; s < SPL; ++s) {
        num += pacc[(size_t)s * NN * OUTF + t];
        z   += pz[(size_t)s * NN + i];
    }
    out[t] = num / z + bias[f];
}

extern "C" void kernel_launch(void* const* d_in, const int* in_sizes, int n_in,
                              void* d_out, int out_size, void* d_ws, size_t ws_size,
                              hipStream_t stream)
{
    const float* x     = (const float*)d_in[0];
    const int*   adj   = (const int*)d_in[1];
    const float* W     = (const float*)d_in[2];
    const float* alpha = (const float*)d_in[3];
    const float* bias  = (const float*)d_in[4];
    float* out = (float*)d_out;

    char* ws = (char*)d_ws;
    size_t off = 0;
    __bf16* WhTt = (__bf16*)(ws + off); off += (size_t)NN * OUTF * 2;   // 1MB
    float* w1 = (float*)(ws + off); off += (size_t)NN * 4;
    float* w2 = (float*)(ws + off); off += (size_t)NN * 4;
    u64* bits = (u64*)(ws + off);   off += (size_t)NN * BPR * 8;        // 8MB
    float* pz   = (float*)(ws + off); off += (size_t)SPL * NN * 4;
    float* pacc = (float*)(ws + off); off += (size_t)SPL * NN * OUTF * 4;

    k12<<<K1B + K2AB, 256, 0, stream>>>(x, W, alpha, adj, WhTt, w1, w2, bits);
    k2b<<<(NN / BM) * SPL, 256, 0, stream>>>(bits, w1, w2, WhTt, pacc, pz);
    k3_final<<<(NN * OUTF) / 256, 256, 0, stream>>>(pacc, pz, bias, out);
}